// Round 1
// baseline (192.645 us; speedup 1.0000x reference)
//
#include <hip/hip_runtime.h>

// ODE-RNN encoder: B=2048, T=64, HID=16, adaptive Tsit5 + GRU.
// 16 lanes/sample, 2 DISTINCT samples/wave (lane halves duplicate), 1024 blocks x 64.
// Early-exit ODE loop (exact). Round 7: halve samples/wave to (a) fill all 1024
// SIMDs (was 512 waves = half the machine idle, OccupancyPercent 5.6%) and
// (b) cut the per-timestep early-exit sync from max-of-4 to max-of-2 adaptive
// step counts (__all spans the wave; duplicated halves have identical tt).
// Round 6: v_pk_fma_f32 dots via DPP all-gather (15 movs -> 8 packed FMAs),
// shared gather for the 3 GRU dots, biases seeded into accumulators,
// amdgpu_waves_per_eu(1,1) to give the allocator the full register budget.

#define T_STEPS 64
#define NB 2048
#define N_ODE_STEPS 16

typedef float v2f __attribute__((ext_vector_type(2)));

__device__ __forceinline__ v2f make2(float a, float b) { v2f r; r.x = a; r.y = b; return r; }

// row_ror:r  => dst lane n gets src lane (n - r) & 15 (within 16-lane row)
#define ROR(x, r) __int_as_float(__builtin_amdgcn_update_dpp( \
    0, __float_as_int(x), 0x120 + (r), 0xF, 0xF, true))

__device__ __forceinline__ float rsum16(float v) {
  v += ROR(v, 8);
  v += ROR(v, 4);
  v += ROR(v, 2);
  v += ROR(v, 1);
  return v;  // all 16 lanes hold the row sum
}

// All-gather: after this, G[p].x = y_{(j-O[2p])&15}, G[p].y = y_{(j-O[2p+1])&15}
// with O = {0,8,4,12,2,10,6,14,1,9,5,13,3,11,7,15}.
__constant__ int O_[16] = {0,8,4,12,2,10,6,14,1,9,5,13,3,11,7,15};

__device__ __forceinline__ void gather16(float y, v2f (&G)[8]) {
  float g0 = y;
  float g1 = ROR(g0, 8);
  float g2 = ROR(g0, 4);
  float g3 = ROR(g1, 4);
  float g4 = ROR(g0, 2);
  float g5 = ROR(g1, 2);
  float g6 = ROR(g2, 2);
  float g7 = ROR(g3, 2);
  float g8  = ROR(g0, 1);
  float g9  = ROR(g1, 1);
  float g10 = ROR(g2, 1);
  float g11 = ROR(g3, 1);
  float g12 = ROR(g4, 1);
  float g13 = ROR(g5, 1);
  float g14 = ROR(g6, 1);
  float g15 = ROR(g7, 1);
  G[0] = make2(g0,  g1);  G[1] = make2(g2,  g3);
  G[2] = make2(g4,  g5);  G[3] = make2(g6,  g7);
  G[4] = make2(g8,  g9);  G[5] = make2(g10, g11);
  G[6] = make2(g12, g13); G[7] = make2(g14, g15);
}

// dot = bias + sum_p W[p].G[p]  (weights pre-permuted to the gather order)
__device__ __forceinline__ float dot8pk(const v2f (&W)[8], const v2f (&G)[8], float bias) {
  v2f a0 = __builtin_elementwise_fma(G[0], W[0], make2(bias, 0.0f));
  v2f a1 = G[1] * W[1];
  a0 = __builtin_elementwise_fma(G[2], W[2], a0);
  a1 = __builtin_elementwise_fma(G[3], W[3], a1);
  a0 = __builtin_elementwise_fma(G[4], W[4], a0);
  a1 = __builtin_elementwise_fma(G[5], W[5], a1);
  a0 = __builtin_elementwise_fma(G[6], W[6], a0);
  a1 = __builtin_elementwise_fma(G[7], W[7], a1);
  v2f s = a0 + a1;
  return s.x + s.y;
}

__device__ __forceinline__ float fast_tanh(float x) {
  // tanh(x) = 1 - 2/(exp(2x)+1); exp via v_exp_f32 (computes 2^x)
  float e = __builtin_amdgcn_exp2f(x * 2.885390081777927f);  // 2*log2(e)
  return fmaf(-2.0f, __builtin_amdgcn_rcpf(e + 1.0f), 1.0f);
}

__device__ __forceinline__ float sigmoid_(float x) {
  float e = __builtin_amdgcn_exp2f(x * -1.4426950408889634f);
  return __builtin_amdgcn_rcpf(1.0f + e);
}

__device__ __forceinline__ float mlp_f(float y,
    const v2f (&w1p)[8], float b1v,
    const v2f (&w2p)[8], float b2v,
    const v2f (&w3p)[8], float b3v) {
  v2f G[8];
  gather16(y, G);
  float h1 = fast_tanh(dot8pk(w1p, G, b1v));
  gather16(h1, G);
  float h2 = fast_tanh(dot8pk(w2p, G, b2v));
  gather16(h2, G);
  return dot8pk(w3p, G, b3v);
}

__global__
__attribute__((amdgpu_flat_work_group_size(64, 64), amdgpu_waves_per_eu(1, 1)))
void odern_kernel(
    const float* __restrict__ x_seq,
    const float* __restrict__ w1, const float* __restrict__ b1,
    const float* __restrict__ w2, const float* __restrict__ b2,
    const float* __restrict__ w3, const float* __restrict__ b3,
    const float* __restrict__ gru_wih, const float* __restrict__ gru_whh,
    const float* __restrict__ gru_b, const float* __restrict__ gru_bn,
    const float* __restrict__ pred_w, const float* __restrict__ pred_b,
    float* __restrict__ out) {
  const int tid = threadIdx.x;
  const int j = tid & 15;        // hidden index owned by this lane
  const int g = tid >> 4;        // group 0..3; groups 2,3 mirror 0,1
  const int b = blockIdx.x * 2 + (g & 1);

  // per-lane weight rows, pre-permuted to the gather order:
  // Wp[p] = { M[j][(j-O[2p])&15], M[j][(j-O[2p+1])&15] }
  v2f w1p[8], w2p[8], w3p[8], whp[8], wzp[8], wnp[8];
#pragma unroll
  for (int p = 0; p < 8; ++p) {
    const int ia = (j - O_[2 * p]) & 15;
    const int ib = (j - O_[2 * p + 1]) & 15;
    w1p[p] = make2(w1[j * 16 + ia], w1[j * 16 + ib]);
    w2p[p] = make2(w2[j * 16 + ia], w2[j * 16 + ib]);
    w3p[p] = make2(w3[j * 16 + ia], w3[j * 16 + ib]);
    whp[p] = make2(gru_whh[j * 16 + ia],        gru_whh[j * 16 + ib]);
    wzp[p] = make2(gru_whh[(16 + j) * 16 + ia], gru_whh[(16 + j) * 16 + ib]);
    wnp[p] = make2(gru_whh[(32 + j) * 16 + ia], gru_whh[(32 + j) * 16 + ib]);
  }
  const float b1v = b1[j], b2v = b2[j], b3v = b3[j];
  const float wih_r0 = gru_wih[j * 2],        wih_r1 = gru_wih[j * 2 + 1];
  const float wih_z0 = gru_wih[(16 + j) * 2], wih_z1 = gru_wih[(16 + j) * 2 + 1];
  const float wih_n0 = gru_wih[(32 + j) * 2], wih_n1 = gru_wih[(32 + j) * 2 + 1];
  const float gb_r = gru_b[j], gb_z = gru_b[16 + j], gb_n = gru_b[32 + j];
  const float bnv = gru_bn[j];
  const float pwv = pred_w[j], pbv = pred_b[0];

  const float* xp = x_seq + (size_t)b * (T_STEPS * 2);

  float h = 0.0f;
#pragma unroll 1
  for (int t = 0; t < T_STEPS; ++t) {
    const float x0 = xp[2 * t];
    const float x1 = xp[2 * t + 1];

    // ---- adaptive Tsit5 from t=0 to t=1, <=16 iterations, early exit ----
    float y = h;
    float tt = 0.0f, dt = 1.0f;
    float k1 = mlp_f(y, w1p, b1v, w2p, b2v, w3p, b3v);
#pragma unroll 1
    for (int s = 0; s < N_ODE_STEPS; ++s) {
      // Once tt == 1.0 for every sample in the wave, remaining reference
      // iterations are bitwise no-ops -> skip. Wave-uniform branch.
      // With 2 distinct samples/wave this is max-of-2, not max-of-4.
      if (__all(tt >= 1.0f)) break;

      const float dt_c = fminf(dt, 1.0f - tt);
      const float d = dt_c;

      float s2 = 0.161f * k1;
      float k2 = mlp_f(fmaf(d, s2, y), w1p, b1v, w2p, b2v, w3p, b3v);

      float s3 = fmaf(0.335480655492357f, k2, -0.008480655492356989f * k1);
      float k3 = mlp_f(fmaf(d, s3, y), w1p, b1v, w2p, b2v, w3p, b3v);

      float s4 = fmaf(4.3622954328695815f, k3,
                 fmaf(-6.359448489975075f, k2, 2.8971530571054935f * k1));
      float k4 = mlp_f(fmaf(d, s4, y), w1p, b1v, w2p, b2v, w3p, b3v);

      float s5 = fmaf(-0.09249506636175525f, k4,
                 fmaf(7.4955393428898365f, k3,
                 fmaf(-11.748883564062828f, k2, 5.325864828439257f * k1)));
      float k5 = mlp_f(fmaf(d, s5, y), w1p, b1v, w2p, b2v, w3p, b3v);

      float s6 = fmaf(-0.028269050394068383f, k5,
                 fmaf(-0.071584973281401f, k4,
                 fmaf(8.159367898576159f, k3,
                 fmaf(-12.92096931784711f, k2, 5.86145544294642f * k1))));
      float k6 = mlp_f(fmaf(d, s6, y), w1p, b1v, w2p, b2v, w3p, b3v);

      float sy = fmaf(2.324710524099774f, k6,
                 fmaf(-3.290069515436081f, k5,
                 fmaf(1.379008574103742f, k4,
                 fmaf(0.4798896504144996f, k3,
                 fmaf(0.01f, k2, 0.09646076681806523f * k1)))));
      float y_new = fmaf(d, sy, y);

      float k7 = mlp_f(y_new, w1p, b1v, w2p, b2v, w3p, b3v);

      float se = fmaf(0.015151515151515152f, k7,
                 fmaf(-0.45808210592918697f, k6,
                 fmaf(0.5823571654525552f, k5,
                 fmaf(-0.1447110071732629f, k4,
                 fmaf(0.007880878010261995f, k3,
                 fmaf(-0.0008164344596567469f, k2, -0.001780011052225777f * k1))))));
      float err = d * se;

      float scale = fmaf(0.01f, fmaxf(fabsf(y), fabsf(y_new)), 0.0001f);
      float r = err * __builtin_amdgcn_rcpf(scale);
      float m = rsum16(r * r) * 0.0625f;   // mean over the 16 hidden dims
      float err2 = fmaxf(m, 1e-16f);

      const bool acc = err2 <= 1.0f;
      y = acc ? y_new : y;
      tt = acc ? tt + dt_c : tt;
      k1 = acc ? k7 : k1;   // FSAL: f(y_new) == k7 bitwise, else keep k1

      // err2^(-0.1) = exp2(-0.1 * log2(err2)); amdgcn logf IS v_log_f32 = log2
      float fac = 0.9f * __builtin_amdgcn_exp2f(-0.1f * __builtin_amdgcn_logf(err2));
      fac = fminf(fmaxf(fac, 0.2f), 10.0f);
      dt = dt_c * fac;
    }

    // ---- GRU update: one shared gather feeds all 3 dots ----
    float ir = fmaf(wih_r1, x1, fmaf(wih_r0, x0, gb_r));
    float iz = fmaf(wih_z1, x1, fmaf(wih_z0, x0, gb_z));
    float in_ = fmaf(wih_n1, x1, fmaf(wih_n0, x0, gb_n));
    v2f G[8];
    gather16(y, G);
    float pre_r = dot8pk(whp, G, ir);    // ir + hr
    float pre_z = dot8pk(wzp, G, iz);    // iz + hz
    float hnb   = dot8pk(wnp, G, bnv);   // hn + bn
    float rg = sigmoid_(pre_r);
    float zg = sigmoid_(pre_z);
    float ng = fast_tanh(fmaf(rg, hnb, in_));
    h = fmaf(zg, y - ng, ng);
  }

  // ---- final projection: out[b] = h . pred_w + pred_b ----
  float ps = rsum16(h * pwv);
  if (j == 0 && g < 2) out[b] = ps + pbv;
}

extern "C" void kernel_launch(void* const* d_in, const int* in_sizes, int n_in,
                              void* d_out, int out_size, void* d_ws, size_t ws_size,
                              hipStream_t stream) {
  (void)in_sizes; (void)n_in; (void)out_size; (void)d_ws; (void)ws_size;
  odern_kernel<<<dim3(NB / 2), dim3(64), 0, stream>>>(
      (const float*)d_in[0],
      (const float*)d_in[1], (const float*)d_in[2],
      (const float*)d_in[3], (const float*)d_in[4],
      (const float*)d_in[5], (const float*)d_in[6],
      (const float*)d_in[7], (const float*)d_in[8],
      (const float*)d_in[9], (const float*)d_in[10],
      (const float*)d_in[11], (const float*)d_in[12],
      (float*)d_out);
}

// Round 2
// 177.169 us; speedup vs baseline: 1.0874x; 1.0874x over previous
//
#include <hip/hip_runtime.h>

// ODE-RNN encoder: B=2048, T=64, HID=16, adaptive Tsit5 + GRU.
// 16 lanes/sample, 4 DISTINCT samples/wave, 512 blocks x 64 (round-0 config:
// round 7 proved (a) step counts are ~uniform across samples -> max-of-4 early
// exit loses nothing, and (b) extra waves/CU cost wall time via shared-CU
// contention, so spreading 1 wave/SIMD over half the machine is optimal).
// Round 8: split each 16-dot into two 8-dots sharing one 8-rotation gather.
// Rotations 8..15 at lane j == rotations 0..7 at lane j-8, so each lane
// computes its own low-half dot (A_j, weights row j) AND the partner's
// high-half dot (B_{j+8}, weights row (j+8)&15) from the SAME 7-DPP gather;
// one ROR(...,8) ships B back. Per layer: 15 DPP -> 8 DPP, shorter tree
// (depth 3), 4 independent FMA chains (A0,A1,B0,B1) for ILP.
// Round 6: v_pk_fma_f32 packed dots, biases seeded into accumulators,
// amdgpu_waves_per_eu(1,1) for the full register budget.

#define T_STEPS 64
#define NB 2048
#define N_ODE_STEPS 16

typedef float v2f __attribute__((ext_vector_type(2)));

__device__ __forceinline__ v2f make2(float a, float b) { v2f r; r.x = a; r.y = b; return r; }

// row_ror:r  => dst lane n gets src lane (n - r) & 15 (within 16-lane row)
#define ROR(x, r) __int_as_float(__builtin_amdgcn_update_dpp( \
    0, __float_as_int(x), 0x120 + (r), 0xF, 0xF, true))

__device__ __forceinline__ float rsum16(float v) {
  v += ROR(v, 8);
  v += ROR(v, 4);
  v += ROR(v, 2);
  v += ROR(v, 1);
  return v;  // all 16 lanes hold the row sum
}

// 8-rotation gather: after this,
//   G[0] = (y_{j-0}, y_{j-2}), G[1] = (y_{j-4}, y_{j-6}),
//   G[2] = (y_{j-1}, y_{j-3}), G[3] = (y_{j-5}, y_{j-7})   (indices mod 16)
// Pair rotation order: PR = {0,2, 4,6, 1,3, 5,7}. 7 DPP, depth 3.
__constant__ int PR_[8] = {0, 2, 4, 6, 1, 3, 5, 7};

__device__ __forceinline__ void gather8(float y, v2f (&G)[4]) {
  float r0 = y;
  float r4 = ROR(r0, 4);
  float r2 = ROR(r0, 2);
  float r6 = ROR(r4, 2);
  float r1 = ROR(r0, 1);
  float r3 = ROR(r2, 1);
  float r5 = ROR(r4, 1);
  float r7 = ROR(r6, 1);
  G[0] = make2(r0, r2);
  G[1] = make2(r4, r6);
  G[2] = make2(r1, r3);
  G[3] = make2(r5, r7);
}

// out_j = bias + sum_{r=0..7} WA.. (row j, rotations 0..7 of y)
//              + sum_{r=8..15}     (row j, rotations 8..15)
// Lane j computes A_j (weights WA = row j) and B_{j+8} (weights WB = row j+8)
// from the same gathered set; ROR by 8 brings B_j back to lane j.
__device__ __forceinline__ float dotAB(const v2f (&WA)[4], const v2f (&WB)[4],
                                       const v2f (&G)[4], float bias) {
  v2f a0 = __builtin_elementwise_fma(G[0], WA[0], make2(bias, 0.0f));
  v2f a1 = G[1] * WA[1];
  v2f b0 = G[0] * WB[0];
  v2f b1 = G[1] * WB[1];
  a0 = __builtin_elementwise_fma(G[2], WA[2], a0);
  a1 = __builtin_elementwise_fma(G[3], WA[3], a1);
  b0 = __builtin_elementwise_fma(G[2], WB[2], b0);
  b1 = __builtin_elementwise_fma(G[3], WB[3], b1);
  v2f as = a0 + a1;
  v2f bs = b0 + b1;
  float bsc = bs.x + bs.y;     // B_{j+8} at lane j
  float bsw = ROR(bsc, 8);     // B_j now at lane j
  return (as.x + as.y) + bsw;
}

__device__ __forceinline__ float fast_tanh(float x) {
  // tanh(x) = 1 - 2/(exp(2x)+1); exp via v_exp_f32 (computes 2^x)
  float e = __builtin_amdgcn_exp2f(x * 2.885390081777927f);  // 2*log2(e)
  return fmaf(-2.0f, __builtin_amdgcn_rcpf(e + 1.0f), 1.0f);
}

__device__ __forceinline__ float sigmoid_(float x) {
  float e = __builtin_amdgcn_exp2f(x * -1.4426950408889634f);
  return __builtin_amdgcn_rcpf(1.0f + e);
}

__device__ __forceinline__ float mlp_f(float u,
    const v2f (&w1a)[4], const v2f (&w1b)[4], float b1v,
    const v2f (&w2a)[4], const v2f (&w2b)[4], float b2v,
    const v2f (&w3a)[4], const v2f (&w3b)[4], float b3v) {
  v2f G[4];
  gather8(u, G);
  float h1 = fast_tanh(dotAB(w1a, w1b, G, b1v));
  gather8(h1, G);
  float h2 = fast_tanh(dotAB(w2a, w2b, G, b2v));
  gather8(h2, G);
  return dotAB(w3a, w3b, G, b3v);
}

__global__
__attribute__((amdgpu_flat_work_group_size(64, 64), amdgpu_waves_per_eu(1, 1)))
void odern_kernel(
    const float* __restrict__ x_seq,
    const float* __restrict__ w1, const float* __restrict__ b1,
    const float* __restrict__ w2, const float* __restrict__ b2,
    const float* __restrict__ w3, const float* __restrict__ b3,
    const float* __restrict__ gru_wih, const float* __restrict__ gru_whh,
    const float* __restrict__ gru_b, const float* __restrict__ gru_bn,
    const float* __restrict__ pred_w, const float* __restrict__ pred_b,
    float* __restrict__ out) {
  const int tid = threadIdx.x;
  const int j = tid & 15;        // hidden index owned by this lane
  const int g = tid >> 4;        // sample-in-wave 0..3
  const int b = blockIdx.x * 4 + g;
  const int jj = (j + 8) & 15;   // partner row for the B half-dot

  // per-lane weight rows in the gather-pair order:
  //   WA[p] = { M[j ][(j-PR[2p])&15], M[j ][(j-PR[2p+1])&15] }
  //   WB[p] = { M[jj][(j-PR[2p])&15], M[jj][(j-PR[2p+1])&15] }
  v2f w1a[4], w1b[4], w2a[4], w2b[4], w3a[4], w3b[4];
  v2f wha[4], whb[4], wza[4], wzb[4], wna[4], wnb[4];
#pragma unroll
  for (int p = 0; p < 4; ++p) {
    const int ia = (j - PR_[2 * p]) & 15;
    const int ib = (j - PR_[2 * p + 1]) & 15;
    w1a[p] = make2(w1[j * 16 + ia],  w1[j * 16 + ib]);
    w1b[p] = make2(w1[jj * 16 + ia], w1[jj * 16 + ib]);
    w2a[p] = make2(w2[j * 16 + ia],  w2[j * 16 + ib]);
    w2b[p] = make2(w2[jj * 16 + ia], w2[jj * 16 + ib]);
    w3a[p] = make2(w3[j * 16 + ia],  w3[j * 16 + ib]);
    w3b[p] = make2(w3[jj * 16 + ia], w3[jj * 16 + ib]);
    wha[p] = make2(gru_whh[j * 16 + ia],         gru_whh[j * 16 + ib]);
    whb[p] = make2(gru_whh[jj * 16 + ia],        gru_whh[jj * 16 + ib]);
    wza[p] = make2(gru_whh[(16 + j) * 16 + ia],  gru_whh[(16 + j) * 16 + ib]);
    wzb[p] = make2(gru_whh[(16 + jj) * 16 + ia], gru_whh[(16 + jj) * 16 + ib]);
    wna[p] = make2(gru_whh[(32 + j) * 16 + ia],  gru_whh[(32 + j) * 16 + ib]);
    wnb[p] = make2(gru_whh[(32 + jj) * 16 + ia], gru_whh[(32 + jj) * 16 + ib]);
  }
  const float b1v = b1[j], b2v = b2[j], b3v = b3[j];
  const float wih_r0 = gru_wih[j * 2],        wih_r1 = gru_wih[j * 2 + 1];
  const float wih_z0 = gru_wih[(16 + j) * 2], wih_z1 = gru_wih[(16 + j) * 2 + 1];
  const float wih_n0 = gru_wih[(32 + j) * 2], wih_n1 = gru_wih[(32 + j) * 2 + 1];
  const float gb_r = gru_b[j], gb_z = gru_b[16 + j], gb_n = gru_b[32 + j];
  const float bnv = gru_bn[j];
  const float pwv = pred_w[j], pbv = pred_b[0];

  const float* xp = x_seq + (size_t)b * (T_STEPS * 2);

  float h = 0.0f;
#pragma unroll 1
  for (int t = 0; t < T_STEPS; ++t) {
    const float x0 = xp[2 * t];
    const float x1 = xp[2 * t + 1];

    // ---- adaptive Tsit5 from t=0 to t=1, <=16 iterations, early exit ----
    float y = h;
    float tt = 0.0f, dt = 1.0f;
    float k1 = mlp_f(y, w1a, w1b, b1v, w2a, w2b, b2v, w3a, w3b, b3v);
#pragma unroll 1
    for (int s = 0; s < N_ODE_STEPS; ++s) {
      // Once tt == 1.0 for every sample in the wave, remaining reference
      // iterations are bitwise no-ops -> skip. Wave-uniform branch.
      if (__all(tt >= 1.0f)) break;

      const float dt_c = fminf(dt, 1.0f - tt);
      const float d = dt_c;

      float s2 = 0.161f * k1;
      float k2 = mlp_f(fmaf(d, s2, y), w1a, w1b, b1v, w2a, w2b, b2v, w3a, w3b, b3v);

      float s3 = fmaf(0.335480655492357f, k2, -0.008480655492356989f * k1);
      float k3 = mlp_f(fmaf(d, s3, y), w1a, w1b, b1v, w2a, w2b, b2v, w3a, w3b, b3v);

      float s4 = fmaf(4.3622954328695815f, k3,
                 fmaf(-6.359448489975075f, k2, 2.8971530571054935f * k1));
      float k4 = mlp_f(fmaf(d, s4, y), w1a, w1b, b1v, w2a, w2b, b2v, w3a, w3b, b3v);

      float s5 = fmaf(-0.09249506636175525f, k4,
                 fmaf(7.4955393428898365f, k3,
                 fmaf(-11.748883564062828f, k2, 5.325864828439257f * k1)));
      float k5 = mlp_f(fmaf(d, s5, y), w1a, w1b, b1v, w2a, w2b, b2v, w3a, w3b, b3v);

      float s6 = fmaf(-0.028269050394068383f, k5,
                 fmaf(-0.071584973281401f, k4,
                 fmaf(8.159367898576159f, k3,
                 fmaf(-12.92096931784711f, k2, 5.86145544294642f * k1))));
      float k6 = mlp_f(fmaf(d, s6, y), w1a, w1b, b1v, w2a, w2b, b2v, w3a, w3b, b3v);

      float sy = fmaf(2.324710524099774f, k6,
                 fmaf(-3.290069515436081f, k5,
                 fmaf(1.379008574103742f, k4,
                 fmaf(0.4798896504144996f, k3,
                 fmaf(0.01f, k2, 0.09646076681806523f * k1)))));
      float y_new = fmaf(d, sy, y);

      float k7 = mlp_f(y_new, w1a, w1b, b1v, w2a, w2b, b2v, w3a, w3b, b3v);

      float se = fmaf(0.015151515151515152f, k7,
                 fmaf(-0.45808210592918697f, k6,
                 fmaf(0.5823571654525552f, k5,
                 fmaf(-0.1447110071732629f, k4,
                 fmaf(0.007880878010261995f, k3,
                 fmaf(-0.0008164344596567469f, k2, -0.001780011052225777f * k1))))));
      float err = d * se;

      float scale = fmaf(0.01f, fmaxf(fabsf(y), fabsf(y_new)), 0.0001f);
      float r = err * __builtin_amdgcn_rcpf(scale);
      float m = rsum16(r * r) * 0.0625f;   // mean over the 16 hidden dims
      float err2 = fmaxf(m, 1e-16f);

      const bool acc = err2 <= 1.0f;
      y = acc ? y_new : y;
      tt = acc ? tt + dt_c : tt;
      k1 = acc ? k7 : k1;   // FSAL: f(y_new) == k7 bitwise, else keep k1

      // err2^(-0.1) = exp2(-0.1 * log2(err2)); amdgcn logf IS v_log_f32 = log2
      float fac = 0.9f * __builtin_amdgcn_exp2f(-0.1f * __builtin_amdgcn_logf(err2));
      fac = fminf(fmaxf(fac, 0.2f), 10.0f);
      dt = dt_c * fac;
    }

    // ---- GRU update: one shared gather feeds all 3 half-split dots ----
    float ir = fmaf(wih_r1, x1, fmaf(wih_r0, x0, gb_r));
    float iz = fmaf(wih_z1, x1, fmaf(wih_z0, x0, gb_z));
    float in_ = fmaf(wih_n1, x1, fmaf(wih_n0, x0, gb_n));
    v2f G[4];
    gather8(y, G);
    float pre_r = dotAB(wha, whb, G, ir);    // ir + hr
    float pre_z = dotAB(wza, wzb, G, iz);    // iz + hz
    float hnb   = dotAB(wna, wnb, G, bnv);   // hn + bn
    float rg = sigmoid_(pre_r);
    float zg = sigmoid_(pre_z);
    float ng = fast_tanh(fmaf(rg, hnb, in_));
    h = fmaf(zg, y - ng, ng);
  }

  // ---- final projection: out[b] = h . pred_w + pred_b ----
  float ps = rsum16(h * pwv);
  if (j == 0) out[b] = ps + pbv;
}

extern "C" void kernel_launch(void* const* d_in, const int* in_sizes, int n_in,
                              void* d_out, int out_size, void* d_ws, size_t ws_size,
                              hipStream_t stream) {
  (void)in_sizes; (void)n_in; (void)out_size; (void)d_ws; (void)ws_size;
  odern_kernel<<<dim3(NB / 4), dim3(64), 0, stream>>>(
      (const float*)d_in[0],
      (const float*)d_in[1], (const float*)d_in[2],
      (const float*)d_in[3], (const float*)d_in[4],
      (const float*)d_in[5], (const float*)d_in[6],
      (const float*)d_in[7], (const float*)d_in[8],
      (const float*)d_in[9], (const float*)d_in[10],
      (const float*)d_in[11], (const float*)d_in[12],
      (float*)d_out);
}

// Round 4
// 171.581 us; speedup vs baseline: 1.1228x; 1.0326x over previous
//
#include <hip/hip_runtime.h>

// ODE-RNN encoder: B=2048, T=64, HID=16, adaptive Tsit5 + GRU.
// Round 9 (resubmit; round-3 bench was an infra failure, kernel re-audited):
// 32 lanes/sample, 2 samples/wave, 1024 blocks x 64 -> fills all 1024 SIMDs
// at 1 wave/SIMD AND halves per-lane work. Lane layout: rows {0,2}=sample0,
// rows {1,3}=sample1; half hf = row>>1. Skewed state: hf=0 lane j holds y_j,
// hf=1 lane j holds y_{j-4}. Per dot, each lane covers 4 cols (rotations
// 0..3 = 3 DPP) x 2 rows (A=j, B=j+8, 4 pk FMAs); B ships via ROR8, halves
// combine via v_permlane32_swap (both-operands-equal pair-sum trick), and a
// row-masked ROR4 on rows 2,3 re-skews. 12 ops/dot vs 21.
// Bias/gate seeds injected once per row (hf=0 chain only; r/z-gate weights
// zeroed at hf=1). rsum16 butterfly is bitwise lane-uniform (IEEE add
// commutativity) and skew-invariant, so accept/tt/dt stay uniform across a
// sample's rows. Rounds 7/8 established: wall time ~ instrs/wave /
// issue-eff(~0.6); step counts ~uniform across samples.

#define T_STEPS 64
#define NB 2048
#define N_ODE_STEPS 16

typedef float v2f __attribute__((ext_vector_type(2)));
typedef int v2i __attribute__((ext_vector_type(2)));

__device__ __forceinline__ v2f make2(float a, float b) { v2f r; r.x = a; r.y = b; return r; }

// row_ror:r  => dst lane n gets src lane (n - r) & 15 (within 16-lane row)
#define ROR(x, r) __int_as_float(__builtin_amdgcn_update_dpp( \
    0, __float_as_int(x), 0x120 + (r), 0xF, 0xF, true))

// rotate-by-4 applied ONLY to rows 2,3 (lanes 32-63); rows 0,1 keep x.
#define ROR4_HI(x) __int_as_float(__builtin_amdgcn_update_dpp( \
    __float_as_int(x), __float_as_int(x), 0x124, 0xC, 0xF, false))

__device__ __forceinline__ float rsum16(float v) {
  v += ROR(v, 8);
  v += ROR(v, 4);
  v += ROR(v, 2);
  v += ROR(v, 1);
  return v;  // all 16 lanes hold the row sum (bitwise lane-uniform)
}

// cross-half combine: returns part + part_from(lane^32).
// With both operands equal, v_permlane32_swap returns {own-half, other-half}
// per lane -> their sum is the pair sum at every lane.
__device__ __forceinline__ float xhalf_sum(float part) {
  v2i pr = __builtin_amdgcn_permlane32_swap(
      __float_as_int(part), __float_as_int(part), false, false);
  return __int_as_float(pr[0]) + __int_as_float(pr[1]);
}

struct G2 { v2f a, b; };

// rotations 0..3 of the (skewed) state within each 16-row: 3 DPP, depth 2
__device__ __forceinline__ G2 gather4(float x) {
  float r1 = ROR(x, 1);
  float r2 = ROR(x, 2);
  float r3 = ROR(r2, 1);
  G2 g; g.a = make2(x, r1); g.b = make2(r2, r3); return g;
}

// Full 16-col dot for row j (at every lane), then re-skewed to state layout.
// WA = row j cols {base-0..-3}, WB = row j+8 same cols (base = j-4*hf).
__device__ __forceinline__ float dotG(const v2f (&WA)[2], const v2f (&WB)[2],
                                      const G2& g, float seed) {
  v2f aa = __builtin_elementwise_fma(g.a, WA[0], make2(seed, 0.0f));
  v2f bb = g.a * WB[0];
  aa = __builtin_elementwise_fma(g.b, WA[1], aa);
  bb = __builtin_elementwise_fma(g.b, WB[1], bb);
  float a  = aa.x + aa.y;          // A partial: row j, this lane's 4 cols
  float bs = bb.x + bb.y;          // B partial: row j+8, this lane's 4 cols
  float part = a + ROR(bs, 8);     // row j partial: 8 cols (this half)
  return ROR4_HI(xhalf_sum(part)); // all 16 cols, re-skewed
}

__device__ __forceinline__ float dotAB(const v2f (&WA)[2], const v2f (&WB)[2],
                                       float x, float seed) {
  G2 g = gather4(x);
  return dotG(WA, WB, g, seed);
}

__device__ __forceinline__ float fast_tanh(float x) {
  float e = __builtin_amdgcn_exp2f(x * 2.885390081777927f);  // 2*log2(e)
  return fmaf(-2.0f, __builtin_amdgcn_rcpf(e + 1.0f), 1.0f);
}

__device__ __forceinline__ float sigmoid_(float x) {
  float e = __builtin_amdgcn_exp2f(x * -1.4426950408889634f);
  return __builtin_amdgcn_rcpf(1.0f + e);
}

__device__ __forceinline__ float mlp_f(float u,
    const v2f (&w1a)[2], const v2f (&w1b)[2], float b1s,
    const v2f (&w2a)[2], const v2f (&w2b)[2], float b2s,
    const v2f (&w3a)[2], const v2f (&w3b)[2], float b3s) {
  float h1 = fast_tanh(dotAB(w1a, w1b, u, b1s));
  float h2 = fast_tanh(dotAB(w2a, w2b, h1, b2s));
  return dotAB(w3a, w3b, h2, b3s);
}

__global__
__attribute__((amdgpu_flat_work_group_size(64, 64), amdgpu_waves_per_eu(1, 1)))
void odern_kernel(
    const float* __restrict__ x_seq,
    const float* __restrict__ w1, const float* __restrict__ b1,
    const float* __restrict__ w2, const float* __restrict__ b2,
    const float* __restrict__ w3, const float* __restrict__ b3,
    const float* __restrict__ gru_wih, const float* __restrict__ gru_whh,
    const float* __restrict__ gru_b, const float* __restrict__ gru_bn,
    const float* __restrict__ pred_w, const float* __restrict__ pred_b,
    float* __restrict__ out) {
  const int tid = threadIdx.x;
  const int j = tid & 15;          // lane position within 16-row
  const int row16 = tid >> 4;      // 0..3
  const int smp = row16 & 1;       // sample-in-wave: rows {0,2}=0, {1,3}=1
  const int hf = row16 >> 1;       // half: 0 = cols j..j-7, 1 = cols j-4..j-15
  const int b = blockIdx.x * 2 + smp;
  const int jj = (j + 8) & 15;     // B-dot row
  const int base = (j - 4 * hf) & 15;  // hidden index of this lane's state slot

  // Per-lane weights: WA[p] = (M[j][c_{2p}], M[j][c_{2p+1}]), c_r = (base-r)&15
  //                   WB[p] = same cols, row jj.
  v2f w1a[2], w1b[2], w2a[2], w2b[2], w3a[2], w3b[2];
  v2f wha[2], whb[2], wza[2], wzb[2], wna[2], wnb[2];
#pragma unroll
  for (int p = 0; p < 2; ++p) {
    const int ca = (base - 2 * p) & 15;
    const int cb = (base - 2 * p - 1) & 15;
    w1a[p] = make2(w1[j * 16 + ca],  w1[j * 16 + cb]);
    w1b[p] = make2(w1[jj * 16 + ca], w1[jj * 16 + cb]);
    w2a[p] = make2(w2[j * 16 + ca],  w2[j * 16 + cb]);
    w2b[p] = make2(w2[jj * 16 + ca], w2[jj * 16 + cb]);
    w3a[p] = make2(w3[j * 16 + ca],  w3[j * 16 + cb]);
    w3b[p] = make2(w3[jj * 16 + ca], w3[jj * 16 + cb]);
    wha[p] = make2(gru_whh[j * 16 + ca],         gru_whh[j * 16 + cb]);
    whb[p] = make2(gru_whh[jj * 16 + ca],        gru_whh[jj * 16 + cb]);
    wza[p] = make2(gru_whh[(16 + j) * 16 + ca],  gru_whh[(16 + j) * 16 + cb]);
    wzb[p] = make2(gru_whh[(16 + jj) * 16 + ca], gru_whh[(16 + jj) * 16 + cb]);
    wna[p] = make2(gru_whh[(32 + j) * 16 + ca],  gru_whh[(32 + j) * 16 + cb]);
    wnb[p] = make2(gru_whh[(32 + jj) * 16 + ca], gru_whh[(32 + jj) * 16 + cb]);
  }
  // Seeds are injected once per output row, via the hf=0 A-chain only.
  const float b1s = hf ? 0.0f : b1[j];
  const float b2s = hf ? 0.0f : b2[j];
  const float b3s = hf ? 0.0f : b3[j];
  // r/z gates: only used as dot seeds -> zero their inputs at hf=1.
  const float wih_r0 = hf ? 0.0f : gru_wih[j * 2];
  const float wih_r1 = hf ? 0.0f : gru_wih[j * 2 + 1];
  const float wih_z0 = hf ? 0.0f : gru_wih[(16 + j) * 2];
  const float wih_z1 = hf ? 0.0f : gru_wih[(16 + j) * 2 + 1];
  const float gb_r = hf ? 0.0f : gru_b[j];
  const float gb_z = hf ? 0.0f : gru_b[16 + j];
  const float bns  = hf ? 0.0f : gru_bn[j];
  // n gate input is used ELEMENTWISE (skewed space) -> base-indexed, all lanes.
  const float wih_n0 = gru_wih[(32 + base) * 2];
  const float wih_n1 = gru_wih[(32 + base) * 2 + 1];
  const float gb_n = gru_b[32 + base];
  const float pwv = pred_w[base], pbv = pred_b[0];

  const float* xp = x_seq + (size_t)b * (T_STEPS * 2);

  float hst = 0.0f;
#pragma unroll 1
  for (int t = 0; t < T_STEPS; ++t) {
    const float x0 = xp[2 * t];
    const float x1 = xp[2 * t + 1];

    // ---- adaptive Tsit5 from t=0 to t=1, <=16 iterations, early exit ----
    float y = hst;
    float tt = 0.0f, dt = 1.0f;
    float k1 = mlp_f(y, w1a, w1b, b1s, w2a, w2b, b2s, w3a, w3b, b3s);
#pragma unroll 1
    for (int s = 0; s < N_ODE_STEPS; ++s) {
      // Wave-uniform early exit (2 samples; accept logic is row-uniform).
      if (__all(tt >= 1.0f)) break;

      const float dt_c = fminf(dt, 1.0f - tt);
      const float d = dt_c;

      float s2 = 0.161f * k1;
      float k2 = mlp_f(fmaf(d, s2, y), w1a, w1b, b1s, w2a, w2b, b2s, w3a, w3b, b3s);

      float s3 = fmaf(0.335480655492357f, k2, -0.008480655492356989f * k1);
      float k3 = mlp_f(fmaf(d, s3, y), w1a, w1b, b1s, w2a, w2b, b2s, w3a, w3b, b3s);

      float s4 = fmaf(4.3622954328695815f, k3,
                 fmaf(-6.359448489975075f, k2, 2.8971530571054935f * k1));
      float k4 = mlp_f(fmaf(d, s4, y), w1a, w1b, b1s, w2a, w2b, b2s, w3a, w3b, b3s);

      float s5 = fmaf(-0.09249506636175525f, k4,
                 fmaf(7.4955393428898365f, k3,
                 fmaf(-11.748883564062828f, k2, 5.325864828439257f * k1)));
      float k5 = mlp_f(fmaf(d, s5, y), w1a, w1b, b1s, w2a, w2b, b2s, w3a, w3b, b3s);

      float s6 = fmaf(-0.028269050394068383f, k5,
                 fmaf(-0.071584973281401f, k4,
                 fmaf(8.159367898576159f, k3,
                 fmaf(-12.92096931784711f, k2, 5.86145544294642f * k1))));
      float k6 = mlp_f(fmaf(d, s6, y), w1a, w1b, b1s, w2a, w2b, b2s, w3a, w3b, b3s);

      float sy = fmaf(2.324710524099774f, k6,
                 fmaf(-3.290069515436081f, k5,
                 fmaf(1.379008574103742f, k4,
                 fmaf(0.4798896504144996f, k3,
                 fmaf(0.01f, k2, 0.09646076681806523f * k1)))));
      float y_new = fmaf(d, sy, y);

      float k7 = mlp_f(y_new, w1a, w1b, b1s, w2a, w2b, b2s, w3a, w3b, b3s);

      float se = fmaf(0.015151515151515152f, k7,
                 fmaf(-0.45808210592918697f, k6,
                 fmaf(0.5823571654525552f, k5,
                 fmaf(-0.1447110071732629f, k4,
                 fmaf(0.007880878010261995f, k3,
                 fmaf(-0.0008164344596567469f, k2, -0.001780011052225777f * k1))))));
      float err = d * se;

      float scale = fmaf(0.01f, fmaxf(fabsf(y), fabsf(y_new)), 0.0001f);
      float r = err * __builtin_amdgcn_rcpf(scale);
      float m = rsum16(r * r) * 0.0625f;   // mean over the 16 hidden dims
      float err2 = fmaxf(m, 1e-16f);

      const bool acc = err2 <= 1.0f;
      y = acc ? y_new : y;
      tt = acc ? tt + dt_c : tt;
      k1 = acc ? k7 : k1;   // FSAL: f(y_new) == k7 bitwise, else keep k1

      float fac = 0.9f * __builtin_amdgcn_exp2f(-0.1f * __builtin_amdgcn_logf(err2));
      fac = fminf(fmaxf(fac, 0.2f), 10.0f);
      dt = dt_c * fac;
    }

    // ---- GRU update: one shared gather feeds all 3 dots ----
    float ir  = fmaf(wih_r1, x1, fmaf(wih_r0, x0, gb_r));   // 0 at hf=1
    float iz  = fmaf(wih_z1, x1, fmaf(wih_z0, x0, gb_z));   // 0 at hf=1
    float in_ = fmaf(wih_n1, x1, fmaf(wih_n0, x0, gb_n));   // skewed, all lanes
    G2 gy = gather4(y);
    float pre_r = dotG(wha, whb, gy, ir);    // ir + hr   (skewed)
    float pre_z = dotG(wza, wzb, gy, iz);    // iz + hz   (skewed)
    float hnb   = dotG(wna, wnb, gy, bns);   // hn + bn   (skewed)
    float rg = sigmoid_(pre_r);
    float zg = sigmoid_(pre_z);
    float ng = fast_tanh(fmaf(rg, hnb, in_));
    hst = fmaf(zg, y - ng, ng);
  }

  // ---- final projection: out[b] = h . pred_w + pred_b ----
  float ps = rsum16(hst * pwv);
  if (hf == 0 && j == 0) out[b] = ps + pbv;   // rows 0,1: one writer per sample
}

extern "C" void kernel_launch(void* const* d_in, const int* in_sizes, int n_in,
                              void* d_out, int out_size, void* d_ws, size_t ws_size,
                              hipStream_t stream) {
  (void)in_sizes; (void)n_in; (void)out_size; (void)d_ws; (void)ws_size;
  odern_kernel<<<dim3(NB / 2), dim3(64), 0, stream>>>(
      (const float*)d_in[0],
      (const float*)d_in[1], (const float*)d_in[2],
      (const float*)d_in[3], (const float*)d_in[4],
      (const float*)d_in[5], (const float*)d_in[6],
      (const float*)d_in[7], (const float*)d_in[8],
      (const float*)d_in[9], (const float*)d_in[10],
      (const float*)d_in[11], (const float*)d_in[12],
      (float*)d_out);
}